// Round 1
// baseline (275.859 us; speedup 1.0000x reference)
//
#include <hip/hip_runtime.h>

// DotProductAttention: causal mask -> [0.7,1,0.7] conv along query axis -> +beta -> softmax -> PV.
// Reduction: masked(-1e9) entries force softmax weight 0 (fp32 underflow, identical in ref) for
// all k > max(q-1,0); on the surviving span the conv is linear in Q:
//   Qeff[q] = 0.7*Q[q-1] + Q[q] + 0.7*Q[q+1]   (missing neighbors dropped: zero padding)
//   out[q]  = softmax_{k<=max(q-1,0)}( dot(Qeff[q],K[k])/8 + beta[k] ) @ V
// => standard flash-style causal attention with effective queries.

constexpr int S_   = 2048;
constexpr int D_   = 64;
constexpr int BQ   = 64;   // query rows per block
constexpr int BK   = 64;   // keys per tile
constexpr int TSTR = 68;   // padded row stride for QT/KT/VS (floats), 68*4B = 16B-aligned
constexpr int PSTR = 20;   // padded row stride for PT (floats), 80B = 16B-aligned

__global__ __launch_bounds__(256, 2)
void attn_fused(const float* __restrict__ Q, const float* __restrict__ K,
                const float* __restrict__ V, const float* __restrict__ beta,
                float* __restrict__ out)
{
    __shared__ float QT[D_][TSTR];      // Qeff transposed: [d][row]
    __shared__ float KT[D_][TSTR];      // K tile transposed: [d][key]
    __shared__ float VS[BK][TSTR];      // V tile row-major: [key][d]
    __shared__ float PT[4][BK][PSTR];   // per-wave P^T: [key][row]

    const int b   = blockIdx.x;
    const int bh  = b >> 5;                      // head index 0..15
    const int idx = b & 31;
    const int qt  = (b < 256) ? idx : (31 - idx); // balance heavy/light q-tiles
    const int q0  = qt * BQ;

    const float* Qh = Q + bh * (S_ * D_);
    const float* Kh = K + bh * (S_ * D_);
    const float* Vh = V + bh * (S_ * D_);
    float*       Oh = out + bh * (S_ * D_);

    const int t    = threadIdx.x;
    const int wave = t >> 6;
    const int lane = t & 63;
    const int rg   = lane >> 4;                  // row group 0..3
    const int cg   = lane & 15;                  // key/d group 0..15
    const int wrow = (wave << 4) + (rg << 2);    // row base within block tile (0..60)

    // ---- stage Qeff^T (once per block) ----
    {
        const int r  = t >> 2;                   // 0..63
        const int dd = (t & 3) << 4;             // 0,16,32,48
        const int q  = q0 + r;
        const bool hp = (q > 0);
        const bool hn = (q + 1 < S_);
        const float wp = hp ? 0.7f : 0.0f;
        const float wn = hn ? 0.7f : 0.0f;
        const float* qc = Qh + q * D_ + dd;
        const float* qp = qc - (hp ? D_ : 0);    // safe addr when absent (weight 0)
        const float* qn = qc + (hn ? D_ : 0);
        #pragma unroll
        for (int i = 0; i < 16; i += 4) {
            float4 c4 = *(const float4*)(qc + i);
            float4 p4 = *(const float4*)(qp + i);
            float4 n4 = *(const float4*)(qn + i);
            QT[dd + i + 0][r] = fmaf(wn, n4.x, fmaf(wp, p4.x, c4.x));
            QT[dd + i + 1][r] = fmaf(wn, n4.y, fmaf(wp, p4.y, c4.y));
            QT[dd + i + 2][r] = fmaf(wn, n4.z, fmaf(wp, p4.z, c4.z));
            QT[dd + i + 3][r] = fmaf(wn, n4.w, fmaf(wp, p4.w, c4.w));
        }
    }

    float m_r[4], l_r[4], O_[4][4];
    #pragma unroll
    for (int i = 0; i < 4; ++i) {
        m_r[i] = -3.0e38f;
        l_r[i] = 0.0f;
        #pragma unroll
        for (int c = 0; c < 4; ++c) O_[i][c] = 0.0f;
    }

    for (int tile = 0; tile <= qt; ++tile) {
        const int k0 = tile * BK;
        __syncthreads();   // prev PV done (and QT staged on first iter)
        // ---- stage K^T and V ----
        {
            const int r  = t >> 2;
            const int dd = (t & 3) << 4;
            const float* kr = Kh + (k0 + r) * D_ + dd;
            const float* vr = Vh + (k0 + r) * D_ + dd;
            #pragma unroll
            for (int i = 0; i < 16; i += 4) {
                float4 k4 = *(const float4*)(kr + i);
                KT[dd + i + 0][r] = k4.x;
                KT[dd + i + 1][r] = k4.y;
                KT[dd + i + 2][r] = k4.z;
                KT[dd + i + 3][r] = k4.w;
                float4 v4 = *(const float4*)(vr + i);
                *(float4*)&VS[r][dd + i] = v4;
            }
        }
        __syncthreads();

        // ---- QK^T: s[c][i], keys k0+cg*4+c, rows q0+wrow+i ----
        float s[4][4];
        #pragma unroll
        for (int c = 0; c < 4; ++c)
            #pragma unroll
            for (int i = 0; i < 4; ++i) s[c][i] = 0.0f;

        #pragma unroll 4
        for (int d = 0; d < D_; ++d) {
            float4 q4 = *(const float4*)&QT[d][wrow];
            float4 k4 = *(const float4*)&KT[d][cg << 2];
            s[0][0] = fmaf(k4.x, q4.x, s[0][0]);
            s[0][1] = fmaf(k4.x, q4.y, s[0][1]);
            s[0][2] = fmaf(k4.x, q4.z, s[0][2]);
            s[0][3] = fmaf(k4.x, q4.w, s[0][3]);
            s[1][0] = fmaf(k4.y, q4.x, s[1][0]);
            s[1][1] = fmaf(k4.y, q4.y, s[1][1]);
            s[1][2] = fmaf(k4.y, q4.z, s[1][2]);
            s[1][3] = fmaf(k4.y, q4.w, s[1][3]);
            s[2][0] = fmaf(k4.z, q4.x, s[2][0]);
            s[2][1] = fmaf(k4.z, q4.y, s[2][1]);
            s[2][2] = fmaf(k4.z, q4.z, s[2][2]);
            s[2][3] = fmaf(k4.z, q4.w, s[2][3]);
            s[3][0] = fmaf(k4.w, q4.x, s[3][0]);
            s[3][1] = fmaf(k4.w, q4.y, s[3][1]);
            s[3][2] = fmaf(k4.w, q4.z, s[3][2]);
            s[3][3] = fmaf(k4.w, q4.w, s[3][3]);
        }

        // scale 1/sqrt(64) + beta
        {
            const float4 b4 = *(const float4*)(beta + k0 + (cg << 2));
            const float bt[4] = {b4.x, b4.y, b4.z, b4.w};
            #pragma unroll
            for (int c = 0; c < 4; ++c)
                #pragma unroll
                for (int i = 0; i < 4; ++i)
                    s[c][i] = fmaf(s[c][i], 0.125f, bt[c]);
        }

        // causal(+1-shift) mask on the diagonal tile: allowed iff k < q, or (q==0 && k==0)
        if (tile == qt) {
            #pragma unroll
            for (int c = 0; c < 4; ++c) {
                const int kg = k0 + (cg << 2) + c;
                #pragma unroll
                for (int i = 0; i < 4; ++i) {
                    const int qg = q0 + wrow + i;
                    const bool ok = (kg < qg) || (qg == 0 && kg == 0);
                    if (!ok) s[c][i] = -1.0e30f;
                }
            }
        }

        // ---- online softmax ----
        float tm[4];
        #pragma unroll
        for (int i = 0; i < 4; ++i) {
            tm[i] = fmaxf(fmaxf(s[0][i], s[1][i]), fmaxf(s[2][i], s[3][i]));
            tm[i] = fmaxf(tm[i], __shfl_xor(tm[i], 1));
            tm[i] = fmaxf(tm[i], __shfl_xor(tm[i], 2));
            tm[i] = fmaxf(tm[i], __shfl_xor(tm[i], 4));
            tm[i] = fmaxf(tm[i], __shfl_xor(tm[i], 8));
        }
        float alpha[4], ts[4];
        #pragma unroll
        for (int i = 0; i < 4; ++i) {
            const float mn = fmaxf(m_r[i], tm[i]);
            alpha[i] = __expf(m_r[i] - mn);
            m_r[i]   = mn;
            ts[i]    = 0.0f;
        }
        #pragma unroll
        for (int c = 0; c < 4; ++c)
            #pragma unroll
            for (int i = 0; i < 4; ++i) {
                const float p = __expf(s[c][i] - m_r[i]);
                s[c][i] = p;
                ts[i] += p;
            }
        #pragma unroll
        for (int i = 0; i < 4; ++i) {
            ts[i] += __shfl_xor(ts[i], 1);
            ts[i] += __shfl_xor(ts[i], 2);
            ts[i] += __shfl_xor(ts[i], 4);
            ts[i] += __shfl_xor(ts[i], 8);
            l_r[i] = fmaf(l_r[i], alpha[i], ts[i]);
        }

        // P^T to LDS (rows contiguous -> b128), rescale O
        #pragma unroll
        for (int c = 0; c < 4; ++c)
            *(float4*)&PT[wave][(cg << 2) + c][rg << 2] =
                make_float4(s[c][0], s[c][1], s[c][2], s[c][3]);
        #pragma unroll
        for (int i = 0; i < 4; ++i)
            #pragma unroll
            for (int c = 0; c < 4; ++c) O_[i][c] *= alpha[i];

        __syncthreads();

        // ---- PV: O[i][c] += sum_k P[row_i][k] * V[k][d=cg*4+c] ----
        #pragma unroll 4
        for (int k = 0; k < BK; ++k) {
            float4 p4 = *(const float4*)&PT[wave][k][rg << 2];
            float4 v4 = *(const float4*)&VS[k][cg << 2];
            O_[0][0] = fmaf(p4.x, v4.x, O_[0][0]);
            O_[0][1] = fmaf(p4.x, v4.y, O_[0][1]);
            O_[0][2] = fmaf(p4.x, v4.z, O_[0][2]);
            O_[0][3] = fmaf(p4.x, v4.w, O_[0][3]);
            O_[1][0] = fmaf(p4.y, v4.x, O_[1][0]);
            O_[1][1] = fmaf(p4.y, v4.y, O_[1][1]);
            O_[1][2] = fmaf(p4.y, v4.z, O_[1][2]);
            O_[1][3] = fmaf(p4.y, v4.w, O_[1][3]);
            O_[2][0] = fmaf(p4.z, v4.x, O_[2][0]);
            O_[2][1] = fmaf(p4.z, v4.y, O_[2][1]);
            O_[2][2] = fmaf(p4.z, v4.z, O_[2][2]);
            O_[2][3] = fmaf(p4.z, v4.w, O_[2][3]);
            O_[3][0] = fmaf(p4.w, v4.x, O_[3][0]);
            O_[3][1] = fmaf(p4.w, v4.y, O_[3][1]);
            O_[3][2] = fmaf(p4.w, v4.z, O_[3][2]);
            O_[3][3] = fmaf(p4.w, v4.w, O_[3][3]);
        }
    }

    // ---- epilogue: normalize + store ----
    #pragma unroll
    for (int i = 0; i < 4; ++i) {
        const float inv = 1.0f / l_r[i];
        float4 o = make_float4(O_[i][0] * inv, O_[i][1] * inv,
                               O_[i][2] * inv, O_[i][3] * inv);
        *(float4*)(Oh + (q0 + wrow + i) * D_ + (cg << 2)) = o;
    }
}

extern "C" void kernel_launch(void* const* d_in, const int* in_sizes, int n_in,
                              void* d_out, int out_size, void* d_ws, size_t ws_size,
                              hipStream_t stream) {
    const float* Q    = (const float*)d_in[0];
    const float* K    = (const float*)d_in[1];
    const float* V    = (const float*)d_in[2];
    const float* beta = (const float*)d_in[3];
    // d_in[4] is the causal mask — deterministic (triu), computed analytically in-kernel.
    float* out = (float*)d_out;

    attn_fused<<<dim3(512), dim3(256), 0, stream>>>(Q, K, V, beta, out);
}

// Round 2
// 142.437 us; speedup vs baseline: 1.9367x; 1.9367x over previous
//
#include <hip/hip_runtime.h>

// DotProductAttention reduced form (verified round 1, absmax 2e-3 in fp32):
//   Qeff[q] = 0.7*Q[q-1] + Q[q] + 0.7*Q[q+1]  (zero pad at edges)
//   out[q]  = softmax_{k <= max(q-1,0)}( Qeff[q]·K[k]/8 + beta[k] ) @ V
// This round: bf16 MFMA. S^T = K·Qeff^T with permuted key->M-row mapping so the
// S^T C-fragment is ALREADY the B-operand fragment for PV (keys 8*quad+0..7 per
// lane). O^T = V^T·P^T accumulated in C-layout. Softmax state per lane (qrow =
// lane&15), replicated across quads via shfl_xor(16/32). exp in log2 domain.

constexpr int S_   = 2048;
constexpr int D_   = 64;
constexpr int LSTR = 72;   // bf16 per LDS row: 144B, 16B-aligned, <=2-way banks

typedef short  bf16x8 __attribute__((ext_vector_type(8)));
typedef float  f32x4  __attribute__((ext_vector_type(4)));

// pack two fp32 -> dword of 2 bf16 (round-half-up), lo in low 16
__device__ __forceinline__ unsigned pk2(float lo, float hi) {
    union { float f; unsigned u; } a, b;
    a.f = lo; b.f = hi;
    return __builtin_amdgcn_perm(b.u + 0x8000u, a.u + 0x8000u, 0x07060302u);
}
__device__ __forceinline__ unsigned short bf1(float x) {
    union { float f; unsigned u; } a; a.f = x;
    return (unsigned short)((a.u + 0x8000u) >> 16);
}

__global__ __launch_bounds__(256, 2)
void attn_mfma(const float* __restrict__ Q, const float* __restrict__ K,
               const float* __restrict__ V, const float* __restrict__ beta,
               float* __restrict__ out)
{
    __shared__ unsigned short Qs [64 * LSTR];  // Qeff bf16 [qrow][d]
    __shared__ unsigned short Ks [64 * LSTR];  // K tile bf16 [key][d]
    __shared__ unsigned short VTs[64 * LSTR];  // V^T tile bf16 [d][key]

    const int b   = blockIdx.x;
    const int bh  = b >> 5;                       // head 0..15
    const int idx = b & 31;
    const int qt  = (b < 256) ? idx : (31 - idx); // heavy/light pairing
    const int q0  = qt << 6;

    const float* Qh = Q + bh * (S_ * D_);
    const float* Kh = K + bh * (S_ * D_);
    const float* Vh = V + bh * (S_ * D_);
    float*       Oh = out + bh * (S_ * D_);

    const int t    = threadIdx.x;
    const int wq   = t >> 6;        // wave -> q-row group
    const int lane = t & 63;
    const int n    = lane & 15;     // qrow-within-wave (N col of MFMA)
    const int qd   = lane >> 4;     // quad
    const int qrow = q0 + (wq << 4) + n;

    // ---- stage Qeff (fp32 compute -> bf16), once per block ----
    {
        const int r  = t >> 2;
        const int dq = (t & 3) << 4;
        const int q  = q0 + r;
        const float wp = (q > 0) ? 0.7f : 0.0f;
        const float wn = (q + 1 < S_) ? 0.7f : 0.0f;
        const float* qc = Qh + q * D_ + dq;
        const float* qp = qc - ((q > 0) ? D_ : 0);
        const float* qn = qc + ((q + 1 < S_) ? D_ : 0);
        unsigned pkd[8];
        #pragma unroll
        for (int i = 0; i < 4; ++i) {
            float4 c4 = *(const float4*)(qc + i * 4);
            float4 p4 = *(const float4*)(qp + i * 4);
            float4 n4 = *(const float4*)(qn + i * 4);
            float e0 = fmaf(wn, n4.x, fmaf(wp, p4.x, c4.x));
            float e1 = fmaf(wn, n4.y, fmaf(wp, p4.y, c4.y));
            float e2 = fmaf(wn, n4.z, fmaf(wp, p4.z, c4.z));
            float e3 = fmaf(wn, n4.w, fmaf(wp, p4.w, c4.w));
            pkd[i*2]   = pk2(e0, e1);
            pkd[i*2+1] = pk2(e2, e3);
        }
        *(uint4*)&Qs[r * LSTR + dq]     = make_uint4(pkd[0], pkd[1], pkd[2], pkd[3]);
        *(uint4*)&Qs[r * LSTR + dq + 8] = make_uint4(pkd[4], pkd[5], pkd[6], pkd[7]);
    }

    // staging assignments
    const int rk = t >> 2;          // K: row (key), coalesced global
    const int dk = (t & 3) << 4;
    const int kv = t & 63;          // V: one key-row per lane (transpose scatter)
    const int dv = (t >> 6) << 4;

    float4 kreg[4], vreg[4];        // register prefetch pipeline
    {
        const float* kr = Kh + rk * D_ + dk;
        const float* vr = Vh + kv * D_ + dv;
        #pragma unroll
        for (int i = 0; i < 4; ++i) {
            kreg[i] = *(const float4*)(kr + i * 4);
            vreg[i] = *(const float4*)(vr + i * 4);
        }
    }

    float m_s = -3.0e38f, l_s = 0.0f;
    f32x4 o0 = {0,0,0,0}, o1 = {0,0,0,0}, o2 = {0,0,0,0}, o3 = {0,0,0,0};
    bf16x8 bq0, bq1;

    constexpr float KSC = 0.125f * 1.44269504088896341f;  // 1/sqrt(64) / ln2
    constexpr float BSC = 1.44269504088896341f;

    for (int tile = 0; tile <= qt; ++tile) {
        __syncthreads();
        // write staged regs -> LDS (bf16)
        {
            unsigned pkd[8];
            #pragma unroll
            for (int i = 0; i < 4; ++i) {
                pkd[i*2]   = pk2(kreg[i].x, kreg[i].y);
                pkd[i*2+1] = pk2(kreg[i].z, kreg[i].w);
            }
            *(uint4*)&Ks[rk * LSTR + dk]     = make_uint4(pkd[0], pkd[1], pkd[2], pkd[3]);
            *(uint4*)&Ks[rk * LSTR + dk + 8] = make_uint4(pkd[4], pkd[5], pkd[6], pkd[7]);
            #pragma unroll
            for (int i = 0; i < 4; ++i) {
                VTs[(dv + i*4 + 0) * LSTR + kv] = bf1(vreg[i].x);
                VTs[(dv + i*4 + 1) * LSTR + kv] = bf1(vreg[i].y);
                VTs[(dv + i*4 + 2) * LSTR + kv] = bf1(vreg[i].z);
                VTs[(dv + i*4 + 3) * LSTR + kv] = bf1(vreg[i].w);
            }
        }
        // prefetch next tile's K/V (consumed next iteration)
        if (tile < qt) {
            const int kb = (tile + 1) << 6;
            const float* kr = Kh + (kb + rk) * D_ + dk;
            const float* vr = Vh + (kb + kv) * D_ + dv;
            #pragma unroll
            for (int i = 0; i < 4; ++i) {
                kreg[i] = *(const float4*)(kr + i * 4);
                vreg[i] = *(const float4*)(vr + i * 4);
            }
        }
        __syncthreads();

        if (tile == 0) {   // Qeff B-frags live in regs for the whole loop
            bq0 = *(const bf16x8*)&Qs[((wq << 4) + n) * LSTR + (qd << 3)];
            bq1 = *(const bf16x8*)&Qs[((wq << 4) + n) * LSTR + 32 + (qd << 3)];
        }

        const int k0 = tile << 6;

        // ---- QK: S^T = K · Qeff^T, permuted key->row mapping ----
        // sc[c][h][r] = S^T[key = k0 + 32c + 8*qd + 4h + r][qrow]
        f32x4 sc[2][2];
        #pragma unroll
        for (int c = 0; c < 2; ++c) {
            #pragma unroll
            for (int h = 0; h < 2; ++h) {
                const int krow = (c << 5) + ((n >> 2) << 3) + (h << 2) + (n & 3);
                bf16x8 a0 = *(const bf16x8*)&Ks[krow * LSTR + (qd << 3)];
                bf16x8 a1 = *(const bf16x8*)&Ks[krow * LSTR + 32 + (qd << 3)];
                f32x4 acc = {0,0,0,0};
                acc = __builtin_amdgcn_mfma_f32_16x16x32_bf16(a0, bq0, acc, 0, 0, 0);
                acc = __builtin_amdgcn_mfma_f32_16x16x32_bf16(a1, bq1, acc, 0, 0, 0);
                sc[c][h] = acc;
            }
        }

        // scale + beta (log2 domain)
        #pragma unroll
        for (int c = 0; c < 2; ++c)
            #pragma unroll
            for (int h = 0; h < 2; ++h) {
                float4 bt = *(const float4*)(beta + k0 + (c << 5) + (qd << 3) + (h << 2));
                sc[c][h][0] = fmaf(sc[c][h][0], KSC, bt.x * BSC);
                sc[c][h][1] = fmaf(sc[c][h][1], KSC, bt.y * BSC);
                sc[c][h][2] = fmaf(sc[c][h][2], KSC, bt.z * BSC);
                sc[c][h][3] = fmaf(sc[c][h][3], KSC, bt.w * BSC);
            }

        // shifted-causal mask on the diagonal tile
        if (tile == qt) {
            #pragma unroll
            for (int c = 0; c < 2; ++c)
                #pragma unroll
                for (int h = 0; h < 2; ++h)
                    #pragma unroll
                    for (int r = 0; r < 4; ++r) {
                        const int key = k0 + (c << 5) + (qd << 3) + (h << 2) + r;
                        const bool ok = (key < qrow) || (qrow == 0 && key == 0);
                        if (!ok) sc[c][h][r] = -1.0e30f;
                    }
        }

        // ---- online softmax (row = qrow, replicated across quads) ----
        float tm = -3.0e38f;
        #pragma unroll
        for (int c = 0; c < 2; ++c)
            #pragma unroll
            for (int h = 0; h < 2; ++h)
                tm = fmaxf(tm, fmaxf(fmaxf(sc[c][h][0], sc[c][h][1]),
                                     fmaxf(sc[c][h][2], sc[c][h][3])));
        tm = fmaxf(tm, __shfl_xor(tm, 16));
        tm = fmaxf(tm, __shfl_xor(tm, 32));
        const float mn = fmaxf(m_s, tm);
        const float al = __builtin_amdgcn_exp2f(m_s - mn);
        m_s = mn;
        float ts = 0.0f;
        #pragma unroll
        for (int c = 0; c < 2; ++c)
            #pragma unroll
            for (int h = 0; h < 2; ++h)
                #pragma unroll
                for (int r = 0; r < 4; ++r) {
                    const float p = __builtin_amdgcn_exp2f(sc[c][h][r] - mn);
                    sc[c][h][r] = p;
                    ts += p;
                }
        ts += __shfl_xor(ts, 16);
        ts += __shfl_xor(ts, 32);
        l_s = fmaf(l_s, al, ts);
        o0 *= al; o1 *= al; o2 *= al; o3 *= al;

        // ---- PV: O^T += V^T · P^T (P already in B-layout per lane) ----
        #pragma unroll
        for (int c = 0; c < 2; ++c) {
            union { unsigned u[4]; bf16x8 v; } pf;
            pf.u[0] = pk2(sc[c][0][0], sc[c][0][1]);
            pf.u[1] = pk2(sc[c][0][2], sc[c][0][3]);
            pf.u[2] = pk2(sc[c][1][0], sc[c][1][1]);
            pf.u[3] = pk2(sc[c][1][2], sc[c][1][3]);
            const int vcol = (c << 5) + (qd << 3);
            o0 = __builtin_amdgcn_mfma_f32_16x16x32_bf16(
                     *(const bf16x8*)&VTs[( 0 + n) * LSTR + vcol], pf.v, o0, 0, 0, 0);
            o1 = __builtin_amdgcn_mfma_f32_16x16x32_bf16(
                     *(const bf16x8*)&VTs[(16 + n) * LSTR + vcol], pf.v, o1, 0, 0, 0);
            o2 = __builtin_amdgcn_mfma_f32_16x16x32_bf16(
                     *(const bf16x8*)&VTs[(32 + n) * LSTR + vcol], pf.v, o2, 0, 0, 0);
            o3 = __builtin_amdgcn_mfma_f32_16x16x32_bf16(
                     *(const bf16x8*)&VTs[(48 + n) * LSTR + vcol], pf.v, o3, 0, 0, 0);
        }
    }

    // ---- epilogue: normalize + store (O^T frag -> row-major out) ----
    const float inv = 1.0f / l_s;
    float* orow = Oh + qrow * D_ + (qd << 2);
    *(float4*)(orow +  0) = make_float4(o0[0]*inv, o0[1]*inv, o0[2]*inv, o0[3]*inv);
    *(float4*)(orow + 16) = make_float4(o1[0]*inv, o1[1]*inv, o1[2]*inv, o1[3]*inv);
    *(float4*)(orow + 32) = make_float4(o2[0]*inv, o2[1]*inv, o2[2]*inv, o2[3]*inv);
    *(float4*)(orow + 48) = make_float4(o3[0]*inv, o3[1]*inv, o3[2]*inv, o3[3]*inv);
}

extern "C" void kernel_launch(void* const* d_in, const int* in_sizes, int n_in,
                              void* d_out, int out_size, void* d_ws, size_t ws_size,
                              hipStream_t stream) {
    const float* Q    = (const float*)d_in[0];
    const float* K    = (const float*)d_in[1];
    const float* V    = (const float*)d_in[2];
    const float* beta = (const float*)d_in[3];
    // d_in[4]: causal mask (deterministic triu) — handled analytically in-kernel.
    float* out = (float*)d_out;

    attn_mfma<<<dim3(512), dim3(256), 0, stream>>>(Q, K, V, beta, out);
}